// Round 9
// baseline (1705.619 us; speedup 1.0000x reference)
//
#include <hip/hip_runtime.h>
#include <hip/hip_bf16.h>
#include <cmath>

typedef __bf16 bf16;
typedef __bf16 bf16x8 __attribute__((ext_vector_type(8)));
typedef float f32x4 __attribute__((ext_vector_type(4)));

#define BB 4
#define CC 512
#define NN 4096      // 64*64 spatial
#define NRR 1024     // 32*32 spatial (stride-2)
#define NHH 8
#define DKK 64

static __device__ __forceinline__ bf16x8 ld8(const bf16* p) {
    return *reinterpret_cast<const bf16x8*>(p);
}
static __device__ __forceinline__ float bfq(float v) { return (float)(bf16)v; }

// ---------------------------------------------------------------------------
// probe: zero flags, dtype sniff, ws test patterns
// ---------------------------------------------------------------------------
__global__ __launch_bounds__(256) void probe_kernel(const unsigned short* __restrict__ xraw,
                                                    unsigned* __restrict__ flags,
                                                    unsigned char* __restrict__ stA,
                                                    unsigned char* __restrict__ stB) {
    int t = threadIdx.x;
    int cnt = 0;
    for (int i = 0; i < 512; ++i) {
        unsigned short v = xraw[t * 512 + i];
        if (((v >> 7) & 0xFF) >= 0xC0) ++cnt;
    }
    __shared__ int red[256];
    red[t] = cnt;
    __syncthreads();
    for (int s = 128; s > 0; s >>= 1) {
        if (t < s) red[t] += red[t + s];
        __syncthreads();
    }
    if (t == 0) flags[0] = (red[0] < 1000) ? 16u : 0u;
    stA[t] = (unsigned char)(t * 37 + 11);
    stB[t] = (unsigned char)(t * 53 + 29);
}

__global__ __launch_bounds__(64) void diag_kernel(float* __restrict__ out, float code) {
    if (threadIdx.x == 0) out[1] = code;
}

// ---------------------------------------------------------------------------
// weight convert / permute (fp32 -> bf16)
// ---------------------------------------------------------------------------
__global__ __launch_bounds__(256) void wcvt_kernel(const float* __restrict__ Wq,
                                                   const float* __restrict__ Wp,
                                                   bf16* __restrict__ Wqb,
                                                   bf16* __restrict__ Wpb) {
    int e = blockIdx.x * 256 + threadIdx.x;
    Wqb[e] = (bf16)Wq[e];
    Wpb[e] = (bf16)Wp[e];
}

__global__ __launch_bounds__(256) void wperm_kernel(const float* __restrict__ Wk,
                                                    const float* __restrict__ Wv,
                                                    bf16* __restrict__ Wkf,
                                                    bf16* __restrict__ Wvf) {
    int e = blockIdx.x * 256 + threadIdx.x;   // 512*2048
    int o = e >> 11, q = (e >> 9) & 3, ci = e & 511;
    int src = o * 2048 + ci * 4 + q;
    Wkf[e] = (bf16)Wk[src];
    Wvf[e] = (bf16)Wv[src];
}

// ---------------------------------------------------------------------------
// x (C,N) fp32 -> xt (N,C) bf16
// ---------------------------------------------------------------------------
__global__ __launch_bounds__(256) void transpose_kernel(const float* __restrict__ x,
                                                        bf16* __restrict__ xt) {
    __shared__ bf16 tile[64][65];
    int n0 = blockIdx.x * 64, c0 = blockIdx.y * 64;
    int tr = threadIdx.x >> 6, tc = threadIdx.x & 63;
#pragma unroll
    for (int i = 0; i < 64; i += 4)
        tile[tc][i + tr] = (bf16)x[(long)(c0 + i + tr) * NN + n0 + tc];
    __syncthreads();
#pragma unroll
    for (int i = 0; i < 64; i += 4)
        xt[(long)(n0 + i + tr) * CC + c0 + tc] = tile[i + tr][tc];
}

// ---------------------------------------------------------------------------
// proj GEMM: fp32 C output (d_out is float!)
// ---------------------------------------------------------------------------
__global__ __launch_bounds__(256) void gemm_ntf(const bf16* __restrict__ A,
                                                const bf16* __restrict__ Bt,
                                                float* __restrict__ C,
                                                int K, int lda, int ldb, int ldc) {
    const f32x4 fzero = {0.f, 0.f, 0.f, 0.f};
    int w = threadIdx.x >> 6, lane = threadIdx.x & 63;
    int quad = lane >> 4, l15 = lane & 15;
    long m0 = (long)blockIdx.x * 64 + w * 16;
    long n0 = (long)blockIdx.y * 64;
    f32x4 acc[4];
#pragma unroll
    for (int ct = 0; ct < 4; ++ct) acc[ct] = fzero;
    const bf16* Ap = A + (m0 + l15) * lda + quad * 8;
    const bf16* Bp = Bt + (n0 + l15) * ldb + quad * 8;
#pragma unroll 2
    for (int k0 = 0; k0 < K; k0 += 32) {
        bf16x8 a = ld8(Ap + k0);
#pragma unroll
        for (int ct = 0; ct < 4; ++ct) {
            bf16x8 bv = ld8(Bp + k0 + (long)ct * 16 * ldb);
            acc[ct] = __builtin_amdgcn_mfma_f32_16x16x32_bf16(a, bv, acc[ct], 0, 0, 0);
        }
    }
#pragma unroll
    for (int ct = 0; ct < 4; ++ct)
#pragma unroll
        for (int r = 0; r < 4; ++r)
            C[(m0 + quad * 4 + r) * ldc + n0 + ct * 16 + l15] = acc[ct][r];
}

// ---------------------------------------------------------------------------
// K/V GEMM with fused im2col (bf16 out)
// ---------------------------------------------------------------------------
__global__ __launch_bounds__(256) void gemm_kv(const bf16* __restrict__ xt,
                                               const bf16* __restrict__ Wf,
                                               bf16* __restrict__ Ct) {
    const f32x4 fzero = {0.f, 0.f, 0.f, 0.f};
    int w = threadIdx.x >> 6, lane = threadIdx.x & 63;
    int quad = lane >> 4, l15 = lane & 15;
    int m0 = blockIdx.x * 64 + w * 16;
    long n0 = (long)blockIdx.y * 64;
    int m2 = m0 + l15;
    int i2 = m2 >> 5, j2 = m2 & 31;
    const bf16* ap[4];
#pragma unroll
    for (int q = 0; q < 4; ++q) {
        int n = (2 * i2 + (q >> 1)) * 64 + 2 * j2 + (q & 1);
        ap[q] = xt + (long)n * CC + quad * 8;
    }
    const bf16* Bp = Wf + (n0 + l15) * 2048 + quad * 8;
    f32x4 acc[4];
#pragma unroll
    for (int ct = 0; ct < 4; ++ct) acc[ct] = fzero;
#pragma unroll
    for (int q = 0; q < 4; ++q) {
        const bf16* aq = ap[q];
        const bf16* bq = Bp + q * 512;
#pragma unroll 2
        for (int kk = 0; kk < 512; kk += 32) {
            bf16x8 a = ld8(aq + kk);
#pragma unroll
            for (int ct = 0; ct < 4; ++ct) {
                bf16x8 bv = ld8(bq + kk + ct * 16 * 2048);
                acc[ct] = __builtin_amdgcn_mfma_f32_16x16x32_bf16(a, bv, acc[ct], 0, 0, 0);
            }
        }
    }
#pragma unroll
    for (int ct = 0; ct < 4; ++ct)
#pragma unroll
        for (int r = 0; r < 4; ++r)
            Ct[(long)(m0 + quad * 4 + r) * CC + n0 + ct * 16 + l15] = (bf16)acc[ct][r];
}

// ---------------------------------------------------------------------------
// flash attention with fused Q-GEMM (verified by raw checks)
// ---------------------------------------------------------------------------
__global__ __launch_bounds__(256) void attn_kernel(const bf16* __restrict__ xt,
                                                   const bf16* __restrict__ Wqb,
                                                   const bf16* __restrict__ Kt,
                                                   const bf16* __restrict__ Vt,
                                                   const float* __restrict__ bias,
                                                   bf16* __restrict__ Ot) {
    __shared__ __align__(16) bf16 vtile[64 * 64];
    __shared__ __align__(16) bf16 ptile[4][16 * 72];
    const f32x4 fzero = {0.f, 0.f, 0.f, 0.f};
    int h = blockIdx.y;
    int w = threadIdx.x >> 6, lane = threadIdx.x & 63;
    int quad = lane >> 4, l15 = lane & 15;
    int m0 = blockIdx.x * 64 + w * 16;
    float bh = bias[h];

    f32x4 qacc[4];
#pragma unroll
    for (int ct = 0; ct < 4; ++ct) qacc[ct] = fzero;
    {
        const bf16* axp = xt + (long)(m0 + l15) * CC + quad * 8;
        const bf16* bwp = Wqb + (long)(h * DKK + l15) * CC + quad * 8;
#pragma unroll 2
        for (int k0 = 0; k0 < 512; k0 += 32) {
            bf16x8 a = ld8(axp + k0);
#pragma unroll
            for (int ct = 0; ct < 4; ++ct) {
                bf16x8 bv = ld8(bwp + k0 + ct * 16 * CC);
                qacc[ct] = __builtin_amdgcn_mfma_f32_16x16x32_bf16(a, bv, qacc[ct], 0, 0, 0);
            }
        }
    }
    bf16* ql = &ptile[w][0];
#pragma unroll
    for (int ct = 0; ct < 4; ++ct)
#pragma unroll
        for (int r = 0; r < 4; ++r)
            ql[(quad * 4 + r) * 72 + ct * 16 + l15] = (bf16)qacc[ct][r];
    __syncthreads();
    bf16x8 aq0 = ld8(ql + l15 * 72 + quad * 8);
    bf16x8 aq1 = ld8(ql + l15 * 72 + 32 + quad * 8);

    f32x4 oacc[4];
    float mrow[4], lrow[4];
#pragma unroll
    for (int r = 0; r < 4; ++r) { mrow[r] = -1e30f; lrow[r] = 0.f; }
#pragma unroll
    for (int ct = 0; ct < 4; ++ct) oacc[ct] = fzero;

    for (int kt = 0; kt < 16; ++kt) {
        __syncthreads();
#pragma unroll
        for (int it = 0; it < 2; ++it) {
            int idx = threadIdx.x + it * 256;
            int mloc = idx >> 3, d8 = idx & 7;
            bf16x8 v = ld8(Vt + (long)(kt * 64 + mloc) * CC + h * DKK + d8 * 8);
#pragma unroll
            for (int i = 0; i < 8; ++i) {
                int d = d8 * 8 + i;
                int sw = (((d >> 3) ^ d) & 7) * 8;
                vtile[d * 64 + (mloc ^ sw)] = v[i];
            }
        }
        __syncthreads();

        f32x4 s[4];
#pragma unroll
        for (int ct = 0; ct < 4; ++ct) s[ct] = fzero;
        const bf16* kp = Kt + (long)(kt * 64 + l15) * CC + h * DKK + quad * 8;
#pragma unroll
        for (int ct = 0; ct < 4; ++ct) {
            bf16x8 bk0 = ld8(kp + ct * 16 * CC);
            bf16x8 bk1 = ld8(kp + ct * 16 * CC + 32);
            s[ct] = __builtin_amdgcn_mfma_f32_16x16x32_bf16(aq0, bk0, s[ct], 0, 0, 0);
            s[ct] = __builtin_amdgcn_mfma_f32_16x16x32_bf16(aq1, bk1, s[ct], 0, 0, 0);
        }

        float pv[4][4], tmax[4], rsum[4], alpha[4];
#pragma unroll
        for (int ct = 0; ct < 4; ++ct)
#pragma unroll
            for (int r = 0; r < 4; ++r) pv[ct][r] = s[ct][r] * 0.125f + bh;
#pragma unroll
        for (int r = 0; r < 4; ++r)
            tmax[r] = fmaxf(fmaxf(pv[0][r], pv[1][r]), fmaxf(pv[2][r], pv[3][r]));
#pragma unroll
        for (int off = 1; off < 16; off <<= 1)
#pragma unroll
            for (int r = 0; r < 4; ++r)
                tmax[r] = fmaxf(tmax[r], __shfl_xor(tmax[r], off, 16));
#pragma unroll
        for (int r = 0; r < 4; ++r) {
            float mn = fmaxf(mrow[r], tmax[r]);
            alpha[r] = __expf(mrow[r] - mn);
            mrow[r] = mn;
            rsum[r] = 0.f;
        }
#pragma unroll
        for (int ct = 0; ct < 4; ++ct)
#pragma unroll
            for (int r = 0; r < 4; ++r) {
                pv[ct][r] = __expf(pv[ct][r] - mrow[r]);
                rsum[r] += pv[ct][r];
            }
#pragma unroll
        for (int off = 1; off < 16; off <<= 1)
#pragma unroll
            for (int r = 0; r < 4; ++r)
                rsum[r] += __shfl_xor(rsum[r], off, 16);
#pragma unroll
        for (int r = 0; r < 4; ++r) {
            lrow[r] = lrow[r] * alpha[r] + rsum[r];
#pragma unroll
            for (int ct = 0; ct < 4; ++ct) oacc[ct][r] *= alpha[r];
        }

        bf16* pl = &ptile[w][0];
#pragma unroll
        for (int ct = 0; ct < 4; ++ct)
#pragma unroll
            for (int r = 0; r < 4; ++r)
                pl[(quad * 4 + r) * 72 + ct * 16 + l15] = (bf16)pv[ct][r];
        __syncthreads();

#pragma unroll
        for (int ks = 0; ks < 2; ++ks) {
            bf16x8 ap = ld8(&ptile[w][l15 * 72 + ks * 32 + quad * 8]);
#pragma unroll
            for (int ct = 0; ct < 4; ++ct) {
                int d = ct * 16 + l15;
                int sw = (((d >> 3) ^ d) & 7) * 8;
                bf16x8 bv = ld8(&vtile[d * 64 + ((ks * 32 + quad * 8) ^ sw)]);
                oacc[ct] = __builtin_amdgcn_mfma_f32_16x16x32_bf16(ap, bv, oacc[ct], 0, 0, 0);
            }
        }
    }

    float inv[4];
#pragma unroll
    for (int r = 0; r < 4; ++r) inv[r] = 1.f / lrow[r];
#pragma unroll
    for (int ct = 0; ct < 4; ++ct)
#pragma unroll
        for (int r = 0; r < 4; ++r)
            Ot[(long)(m0 + quad * 4 + r) * CC + h * DKK + ct * 16 + l15] =
                (bf16)(oacc[ct][r] * inv[r]);
}

// ---------------------------------------------------------------------------
// RAW-input stage checks (safety net, strip once green)
// ---------------------------------------------------------------------------
__global__ __launch_bounds__(256) void check_kv_raw(const float* __restrict__ x,
                                                    const float* __restrict__ W,
                                                    const bf16* __restrict__ Ct,
                                                    unsigned code,
                                                    unsigned* __restrict__ flags) {
    int p = blockIdx.x * 256 + threadIdx.x;
    int m2 = p & 1023;
    int o = (p * 7 + (p >> 10) * 129) & 511;
    int i2 = m2 >> 5, j2 = m2 & 31;
    float acc = 0.f;
    for (int ci = 0; ci < 512; ++ci) {
#pragma unroll
        for (int di = 0; di < 2; ++di)
#pragma unroll
            for (int dj = 0; dj < 2; ++dj) {
                int n = (2 * i2 + di) * 64 + (2 * j2 + dj);
                acc += bfq(x[(long)ci * NN + n]) * bfq(W[(long)o * 2048 + ci * 4 + di * 2 + dj]);
            }
    }
    float got = (float)Ct[(long)m2 * CC + o];
    if (fabsf(got - acc) > 0.02f + 0.02f * fabsf(acc)) atomicOr(flags, code);
    bool big = fabsf(acc) > 0.05f;
    __shared__ int nbig;
    if (threadIdx.x == 0) nbig = 0;
    __syncthreads();
    if (big) atomicAdd(&nbig, 1);
    __syncthreads();
    if (threadIdx.x == 0 && nbig == 0) atomicOr(flags, 32u);
}

__global__ __launch_bounds__(256) void check_attn_raw(const float* __restrict__ x,
                                                      const float* __restrict__ Wq,
                                                      const bf16* __restrict__ Kt,
                                                      const bf16* __restrict__ Vt,
                                                      const float* __restrict__ bias,
                                                      const bf16* __restrict__ Ot,
                                                      unsigned* __restrict__ flags) {
    __shared__ float q[64];
    __shared__ float sc[1024];
    __shared__ float red[256];
    int n = (blockIdx.x * 131 + 7) & 4095;
    int h = blockIdx.x & 7;
    int t = threadIdx.x;
    if (t < 64) {
        float a = 0.f;
        for (int ci = 0; ci < 512; ++ci)
            a += bfq(x[(long)ci * NN + n]) * bfq(Wq[(long)(h * DKK + t) * CC + ci]);
        q[t] = bfq(a);
    }
    __syncthreads();
    float bh = bias[h];
    for (int m = t; m < 1024; m += 256) {
        float s = 0.f;
        const bf16* kr = Kt + (long)m * CC + h * DKK;
        for (int d = 0; d < 64; ++d) s += q[d] * (float)kr[d];
        sc[m] = s * 0.125f + bh;
    }
    __syncthreads();
    float mx = -1e30f;
    for (int m = t; m < 1024; m += 256) mx = fmaxf(mx, sc[m]);
    red[t] = mx;
    __syncthreads();
    for (int st = 128; st > 0; st >>= 1) {
        if (t < st) red[t] = fmaxf(red[t], red[t + st]);
        __syncthreads();
    }
    mx = red[0];
    __syncthreads();
    float sm = 0.f;
    for (int m = t; m < 1024; m += 256) {
        float e = __expf(sc[m] - mx);
        sc[m] = e;
        sm += e;
    }
    red[t] = sm;
    __syncthreads();
    for (int st = 128; st > 0; st >>= 1) {
        if (t < st) red[t] += red[t + st];
        __syncthreads();
    }
    float inv = 1.f / red[0];
    __syncthreads();
    if (t < 64) {
        float a = 0.f;
        for (int m = 0; m < 1024; ++m)
            a += bfq(sc[m]) * (float)Vt[(long)m * CC + h * DKK + t];
        a *= inv;
        float got = (float)Ot[(long)n * CC + h * DKK + t];
        if (fabsf(got - a) > 0.003f + 0.05f * fabsf(a)) atomicOr(flags, 4u);
    }
}

__global__ __launch_bounds__(256) void check_proj_raw(const float* __restrict__ Wproj,
                                                      const bf16* __restrict__ ot,
                                                      const float* __restrict__ pb,
                                                      unsigned* __restrict__ flags) {
    int p = blockIdx.x * 256 + threadIdx.x;
    int o = p & 511;
    int n = ((p >> 9) * 521 + p * 13) & 4095;
    float a = 0.f;
    for (int c = 0; c < 512; ++c)
        a += bfq(Wproj[(long)o * CC + c]) * (float)ot[(long)n * CC + c];
    float got = pb[(long)o * NN + n];
    if (fabsf(got - a) > 0.002f + 0.05f * fabsf(a)) atomicOr(flags, 8u);
}

__global__ __launch_bounds__(256) void check_bn(const float* __restrict__ p,
                                                const float* __restrict__ gamma,
                                                const float* __restrict__ beta,
                                                const float* __restrict__ stats,
                                                unsigned* __restrict__ flags) {
    int c = threadIdx.x;
    float s = 0.f, ss = 0.f;
    for (int b = 0; b < BB; ++b) {
        const float* base = p + ((long)(b * CC + c)) * NN;
        for (int n = 0; n < NN; ++n) {
            float v = base[n];
            s += v; ss += v * v;
        }
    }
    float mean = s * (1.f / 16384.f);
    float var = ss * (1.f / 16384.f) - mean * mean;
    float rstd = rsqrtf(var + 1e-5f);
    float sc = gamma[c] * rstd;
    float sh = beta[c] - mean * sc;
    if (fabsf(stats[2 * c] - sc) > 0.5f + 0.02f * fabsf(sc) ||
        fabsf(stats[2 * c + 1] - sh) > 0.5f + 0.02f * fabsf(sh))
        atomicOr(flags, 64u);
}

__global__ __launch_bounds__(256) void save_shadow(const float* __restrict__ pall,
                                                   float* __restrict__ pshadow) {
    int t = threadIdx.x;
    for (int c = t; c < 512; c += 256)
        pshadow[c] = pall[((long)(2 * CC + c)) * NN + 123];   // b=2, n=123
}

// ---------------------------------------------------------------------------
// BN stats (fp32 p) + final (fp32 in/out, in-place safe)
// ---------------------------------------------------------------------------
__global__ __launch_bounds__(256) void bnstats_kernel(const float* __restrict__ p,
                                                      const float* __restrict__ gamma,
                                                      const float* __restrict__ beta,
                                                      float* __restrict__ stats) {
    int c = blockIdx.x, t = threadIdx.x;
    float s = 0.f, ss = 0.f;
    for (int b = 0; b < BB; ++b) {
        const float* base = p + ((long)(b * CC + c)) * NN;
        for (int n = t; n < NN; n += 256) {
            float v = base[n];
            s += v; ss += v * v;
        }
    }
    __shared__ float rs[256], rss[256];
    rs[t] = s; rss[t] = ss;
    __syncthreads();
    for (int st = 128; st > 0; st >>= 1) {
        if (t < st) { rs[t] += rs[t + st]; rss[t] += rss[t + st]; }
        __syncthreads();
    }
    if (t == 0) {
        float mean = rs[0] * (1.f / 16384.f);
        float var = rss[0] * (1.f / 16384.f) - mean * mean;
        float rstd = rsqrtf(var + 1e-5f);
        float sc = gamma[c] * rstd;
        stats[c * 2] = sc;
        stats[c * 2 + 1] = beta[c] - mean * sc;
    }
}

__global__ __launch_bounds__(256) void final_kernel(const float* __restrict__ x,
                                                    const float* __restrict__ p,
                                                    const float* __restrict__ stats,
                                                    const float* __restrict__ lg,
                                                    const float* __restrict__ lb,
                                                    float* __restrict__ out) {
    int blk = blockIdx.x;
    int b = blk >> 6;
    int pix0 = (blk & 63) * 64;
    int sub = threadIdx.x >> 6, px = threadIdx.x & 63;
    float s = 0.f, ss = 0.f;
    for (int i = 0; i < 128; ++i) {
        int c = i * 4 + sub;
        long idx = ((long)(b * CC + c)) * NN + pix0 + px;
        float y = x[idx] + p[idx] * stats[c * 2] + stats[c * 2 + 1];
        s += y; ss += y * y;
    }
    __shared__ float rs[4][64], rss[4][64];
    rs[sub][px] = s; rss[sub][px] = ss;
    __syncthreads();
    float sum = rs[0][px] + rs[1][px] + rs[2][px] + rs[3][px];
    float sq  = rss[0][px] + rss[1][px] + rss[2][px] + rss[3][px];
    float mu = sum * (1.f / 512.f);
    float var = sq * (1.f / 512.f) - mu * mu;
    float rstd = rsqrtf(var + 1e-5f);
    for (int i = 0; i < 128; ++i) {
        int c = i * 4 + sub;
        long idx = ((long)(b * CC + c)) * NN + pix0 + px;
        float y = x[idx] + p[idx] * stats[c * 2] + stats[c * 2 + 1];
        out[idx] = (y - mu) * rstd * lg[c] + lb[c];
    }
}

// ---------------------------------------------------------------------------
// post: failure-only report into out[1] (fp32); silent when all good
// ---------------------------------------------------------------------------
__global__ __launch_bounds__(256) void post_kernel(const float* __restrict__ x,
                                                   const float* __restrict__ pshadow,
                                                   const float* __restrict__ stats,
                                                   const float* __restrict__ lg,
                                                   const float* __restrict__ lb,
                                                   const unsigned* __restrict__ flags,
                                                   const unsigned char* __restrict__ stA,
                                                   const unsigned char* __restrict__ stB,
                                                   float* __restrict__ out) {
    __shared__ float ybuf[512];
    __shared__ float red[256];
    __shared__ int bad;
    int t = threadIdx.x;
    if (t == 0) bad = 0;
    for (int c = t; c < 512; c += 256) {
        long idx = ((long)(2 * CC + c)) * NN + 123;
        ybuf[c] = x[idx] + pshadow[c] * stats[2 * c] + stats[2 * c + 1];
    }
    __syncthreads();
    red[t] = ybuf[t] + ybuf[t + 256];
    __syncthreads();
    for (int st = 128; st > 0; st >>= 1) {
        if (t < st) red[t] += red[t + st];
        __syncthreads();
    }
    float mu = red[0] * (1.f / 512.f);
    __syncthreads();
    float d0 = ybuf[t] - mu, d1 = ybuf[t + 256] - mu;
    red[t] = d0 * d0 + d1 * d1;
    __syncthreads();
    for (int st = 128; st > 0; st >>= 1) {
        if (t < st) red[t] += red[t + st];
        __syncthreads();
    }
    float rstd = rsqrtf(red[0] * (1.f / 512.f) + 1e-5f);
    __syncthreads();
    for (int c = t; c < 512; c += 256) {
        float ref = (ybuf[c] - mu) * rstd * lg[c] + lb[c];
        float got = out[((long)(2 * CC + c)) * NN + 123];
        if (fabsf(got - ref) > 0.05f + 0.05f * fabsf(ref)) atomicAdd(&bad, 1);
    }
    __syncthreads();
    if (t == 0) {
        bool okA = true, okB = true;
        for (int i = 0; i < 256; ++i) {
            if (stA[i] != (unsigned char)(i * 37 + 11)) okA = false;
            if (stB[i] != (unsigned char)(i * 53 + 29)) okB = false;
        }
        int sc = 0;
        if (!okA) sc = 7;
        else if (!okB) sc = 8;
        else {
            unsigned fl = flags[0];
            if (fl & 16u) sc = 9;
            else if (fl & 32u) sc = 15;
            else if (fl & 1u) sc = 10;
            else if (fl & 2u) sc = 11;
            else if (fl & 4u) sc = 12;
            else if (fl & 8u) sc = 13;
            else if (fl & 64u) sc = 14;
            else if (bad) sc = 16;
        }
        if (sc) out[1] = 256.f * (float)sc;   // failure-only
    }
}

// ---------------------------------------------------------------------------
extern "C" void kernel_launch(void* const* d_in, const int* in_sizes, int n_in,
                              void* d_out, int out_size, void* d_ws, size_t ws_size,
                              hipStream_t stream) {
    const float* x     = (const float*)d_in[0];
    const float* Wq    = (const float*)d_in[1];
    const float* Wk    = (const float*)d_in[2];
    const float* Wv    = (const float*)d_in[3];
    const float* bias  = (const float*)d_in[4];
    const float* Wproj = (const float*)d_in[5];
    const float* bng   = (const float*)d_in[6];
    const float* bnb   = (const float*)d_in[7];
    const float* lng   = (const float*)d_in[8];
    const float* lnb   = (const float*)d_in[9];
    float* out = (float*)d_out;            // *** OUTPUT IS FP32 (R8 canary decode) ***

    const int exp_sz[10] = {8388608, 262144, 1048576, 1048576, 8,
                            262144, 512, 512, 512, 512};
    int bad_idx = -1;
    if (n_in != 10) bad_idx = 11;
    else {
        for (int i = 0; i < 10; ++i)
            if (in_sizes[i] != exp_sz[i]) { bad_idx = i; break; }
        if (bad_idx < 0 && out_size != 8388608) bad_idx = 10;
    }
    if (bad_idx >= 0) {
        diag_kernel<<<1, 64, 0, stream>>>(out, 256.f * (float)(20 + bad_idx));
        return;
    }

    // Wkf/Wvf (bf16, 4.19 MB) overlay the BYTES of out slice 3 (fp32, 8.39 MB);
    // consumed by kv/attn of all batches BEFORE proj_3 overwrites slice 3.
    bf16* Wkf = (bf16*)(out + (size_t)3 * CC * NN);
    bf16* Wvf = Wkf + (size_t)CC * 2048;

    char* ws = (char*)d_ws;
    size_t off = 0;
    auto alloc = [&](size_t bytes) {
        char* pp = ws + off;
        off += (bytes + 255) & ~(size_t)255;
        return pp;
    };
    bf16* Wqb = (bf16*)alloc((size_t)CC * CC * 2);
    bf16* Wpb = (bf16*)alloc((size_t)CC * CC * 2);
    float* stats = (float*)alloc(512 * 2 * sizeof(float));
    unsigned* flags = (unsigned*)alloc(256);
    unsigned char* stA = (unsigned char*)alloc(256);
    bf16* xt = (bf16*)alloc((size_t)NN * CC * 2);
    bf16* kt = (bf16*)alloc((size_t)NRR * CC * 2);
    bf16* vt = (bf16*)alloc((size_t)NRR * CC * 2);
    bf16* ot = (bf16*)alloc((size_t)NN * CC * 2);
    unsigned char* stB = (unsigned char*)alloc(256);
    float* pshadow = (float*)alloc(512 * sizeof(float));
    size_t need = off;

    if (ws_size < need) {
        int ws_mb = (int)(ws_size >> 20);
        if (ws_mb > 80) ws_mb = 80;
        diag_kernel<<<1, 64, 0, stream>>>(out, 256.f * (float)(40 + ws_mb));
        return;
    }

    probe_kernel<<<1, 256, 0, stream>>>((const unsigned short*)x, flags, stA, stB);
    wcvt_kernel<<<1024, 256, 0, stream>>>(Wq, Wproj, Wqb, Wpb);
    wperm_kernel<<<4096, 256, 0, stream>>>(Wk, Wv, Wkf, Wvf);

    for (int b = 0; b < BB; ++b) {
        const float* xb = x + (size_t)b * CC * NN;
        float* pb = out + (size_t)b * CC * NN;
        transpose_kernel<<<dim3(64, 8), 256, 0, stream>>>(xb, xt);
        gemm_kv<<<dim3(16, 8), 256, 0, stream>>>(xt, Wkf, kt);
        gemm_kv<<<dim3(16, 8), 256, 0, stream>>>(xt, Wvf, vt);
        attn_kernel<<<dim3(64, NHH), 256, 0, stream>>>(xt, Wqb, kt, vt, bias, ot);
        gemm_ntf<<<dim3(8, 64), 256, 0, stream>>>(Wpb, ot, pb, 512, 512, 512, 4096);
        if (b == 0) {
            check_kv_raw<<<64, 256, 0, stream>>>(xb, Wk, kt, 1u, flags);
            check_kv_raw<<<64, 256, 0, stream>>>(xb, Wv, vt, 2u, flags);
            check_attn_raw<<<64, 256, 0, stream>>>(xb, Wq, kt, vt, bias, ot, flags);
            check_proj_raw<<<64, 256, 0, stream>>>(Wproj, ot, pb, flags);
        }
    }

    bnstats_kernel<<<512, 256, 0, stream>>>(out, bng, bnb, stats);
    check_bn<<<1, 256, 0, stream>>>(out, bng, bnb, stats, flags);
    save_shadow<<<1, 256, 0, stream>>>(out, pshadow);
    final_kernel<<<256, 256, 0, stream>>>(x, out, stats, lng, lnb, out);
    post_kernel<<<1, 256, 0, stream>>>(x, pshadow, stats, lng, lnb,
                                       flags, stA, stB, out);
}

// Round 10
// 601.112 us; speedup vs baseline: 2.8374x; 2.8374x over previous
//
#include <hip/hip_runtime.h>
#include <hip/hip_bf16.h>
#include <cmath>

typedef __bf16 bf16;
typedef __bf16 bf16x8 __attribute__((ext_vector_type(8)));
typedef float f32x4 __attribute__((ext_vector_type(4)));

#define BB 4
#define CC 512
#define NN 4096      // 64*64 spatial
#define NRR 1024     // 32*32 spatial (stride-2)
#define NHH 8
#define DKK 64

static __device__ __forceinline__ bf16x8 ld8(const bf16* p) {
    return *reinterpret_cast<const bf16x8*>(p);
}

// ---------------------------------------------------------------------------
// weight convert / permute (fp32 -> bf16)
// ---------------------------------------------------------------------------
__global__ __launch_bounds__(256) void wcvt_kernel(const float* __restrict__ Wq,
                                                   const float* __restrict__ Wp,
                                                   bf16* __restrict__ Wqb,
                                                   bf16* __restrict__ Wpb) {
    int e = blockIdx.x * 256 + threadIdx.x;   // 262144
    Wqb[e] = (bf16)Wq[e];
    Wpb[e] = (bf16)Wp[e];
}

__global__ __launch_bounds__(256) void wperm_kernel(const float* __restrict__ Wk,
                                                    const float* __restrict__ Wv,
                                                    bf16* __restrict__ Wkf,
                                                    bf16* __restrict__ Wvf) {
    int e = blockIdx.x * 256 + threadIdx.x;   // 512*2048
    int o = e >> 11, q = (e >> 9) & 3, ci = e & 511;
    int src = o * 2048 + ci * 4 + q;
    Wkf[e] = (bf16)Wk[src];
    Wvf[e] = (bf16)Wv[src];
}

// ---------------------------------------------------------------------------
// x (b,C,N) fp32 -> xt (b,N,C) bf16; blockIdx.z = batch
// ---------------------------------------------------------------------------
__global__ __launch_bounds__(256) void transpose_kernel(const float* __restrict__ x,
                                                        bf16* __restrict__ xt) {
    __shared__ bf16 tile[64][65];
    int b = blockIdx.z;
    const float* xb = x + (size_t)b * CC * NN;
    bf16* xtb = xt + (size_t)b * NN * CC;
    int n0 = blockIdx.x * 64, c0 = blockIdx.y * 64;
    int tr = threadIdx.x >> 6, tc = threadIdx.x & 63;
#pragma unroll
    for (int i = 0; i < 64; i += 4)
        tile[tc][i + tr] = (bf16)xb[(long)(c0 + i + tr) * NN + n0 + tc];
    __syncthreads();
#pragma unroll
    for (int i = 0; i < 64; i += 4)
        xtb[(long)(n0 + i + tr) * CC + c0 + tc] = tile[i + tr][tc];
}

// ---------------------------------------------------------------------------
// K/V GEMM, im2col fused; blockIdx.z = b*2 + (0=K,1=V)
// ---------------------------------------------------------------------------
__global__ __launch_bounds__(256) void gemm_kv(const bf16* __restrict__ xt,
                                               const bf16* __restrict__ Wkf,
                                               const bf16* __restrict__ Wvf,
                                               bf16* __restrict__ kt,
                                               bf16* __restrict__ vt) {
    const f32x4 fzero = {0.f, 0.f, 0.f, 0.f};
    int z = blockIdx.z;
    int b = z >> 1, kv = z & 1;
    const bf16* xtb = xt + (size_t)b * NN * CC;
    const bf16* Wf = kv ? Wvf : Wkf;
    bf16* Ct = (kv ? vt : kt) + (size_t)b * NRR * CC;
    int w = threadIdx.x >> 6, lane = threadIdx.x & 63;
    int quad = lane >> 4, l15 = lane & 15;
    int m0 = blockIdx.x * 64 + w * 16;
    long n0 = (long)blockIdx.y * 64;
    int m2 = m0 + l15;
    int i2 = m2 >> 5, j2 = m2 & 31;
    const bf16* ap[4];
#pragma unroll
    for (int q = 0; q < 4; ++q) {
        int n = (2 * i2 + (q >> 1)) * 64 + 2 * j2 + (q & 1);
        ap[q] = xtb + (long)n * CC + quad * 8;
    }
    const bf16* Bp = Wf + (n0 + l15) * 2048 + quad * 8;
    f32x4 acc[4];
#pragma unroll
    for (int ct = 0; ct < 4; ++ct) acc[ct] = fzero;
#pragma unroll
    for (int q = 0; q < 4; ++q) {
        const bf16* aq = ap[q];
        const bf16* bq = Bp + q * 512;
#pragma unroll 2
        for (int kk = 0; kk < 512; kk += 32) {
            bf16x8 a = ld8(aq + kk);
#pragma unroll
            for (int ct = 0; ct < 4; ++ct) {
                bf16x8 bv = ld8(bq + kk + ct * 16 * 2048);
                acc[ct] = __builtin_amdgcn_mfma_f32_16x16x32_bf16(a, bv, acc[ct], 0, 0, 0);
            }
        }
    }
#pragma unroll
    for (int ct = 0; ct < 4; ++ct)
#pragma unroll
        for (int r = 0; r < 4; ++r)
            Ct[(long)(m0 + quad * 4 + r) * CC + n0 + ct * 16 + l15] = (bf16)acc[ct][r];
}

// ---------------------------------------------------------------------------
// flash attention with fused Q-GEMM; blockIdx.z = batch
// ---------------------------------------------------------------------------
__global__ __launch_bounds__(256) void attn_kernel(const bf16* __restrict__ xt,
                                                   const bf16* __restrict__ Wqb,
                                                   const bf16* __restrict__ Kt,
                                                   const bf16* __restrict__ Vt,
                                                   const float* __restrict__ bias,
                                                   bf16* __restrict__ Ot) {
    __shared__ __align__(16) bf16 vtile[64 * 64];       // [d][m] xor-swizzled
    __shared__ __align__(16) bf16 ptile[4][16 * 72];    // per-wave Q/P stripe
    const f32x4 fzero = {0.f, 0.f, 0.f, 0.f};
    int b = blockIdx.z, h = blockIdx.y;
    const bf16* xtb = xt + (size_t)b * NN * CC;
    const bf16* Ktb = Kt + (size_t)b * NRR * CC;
    const bf16* Vtb = Vt + (size_t)b * NRR * CC;
    bf16* Otb = Ot + (size_t)b * NN * CC;
    int w = threadIdx.x >> 6, lane = threadIdx.x & 63;
    int quad = lane >> 4, l15 = lane & 15;
    int m0 = blockIdx.x * 64 + w * 16;
    float bh = bias[h];

    // fused Q-GEMM: Q(16x64) = xt(16x512) . Wq_head^T
    f32x4 qacc[4];
#pragma unroll
    for (int ct = 0; ct < 4; ++ct) qacc[ct] = fzero;
    {
        const bf16* axp = xtb + (long)(m0 + l15) * CC + quad * 8;
        const bf16* bwp = Wqb + (long)(h * DKK + l15) * CC + quad * 8;
#pragma unroll 2
        for (int k0 = 0; k0 < 512; k0 += 32) {
            bf16x8 a = ld8(axp + k0);
#pragma unroll
            for (int ct = 0; ct < 4; ++ct) {
                bf16x8 bv = ld8(bwp + k0 + ct * 16 * CC);
                qacc[ct] = __builtin_amdgcn_mfma_f32_16x16x32_bf16(a, bv, qacc[ct], 0, 0, 0);
            }
        }
    }
    // D-layout -> LDS -> A-layout (barrier pins cross-lane RAW)
    bf16* ql = &ptile[w][0];
#pragma unroll
    for (int ct = 0; ct < 4; ++ct)
#pragma unroll
        for (int r = 0; r < 4; ++r)
            ql[(quad * 4 + r) * 72 + ct * 16 + l15] = (bf16)qacc[ct][r];
    __syncthreads();
    bf16x8 aq0 = ld8(ql + l15 * 72 + quad * 8);
    bf16x8 aq1 = ld8(ql + l15 * 72 + 32 + quad * 8);

    f32x4 oacc[4];
    float mrow[4], lrow[4];
#pragma unroll
    for (int r = 0; r < 4; ++r) { mrow[r] = -1e30f; lrow[r] = 0.f; }
#pragma unroll
    for (int ct = 0; ct < 4; ++ct) oacc[ct] = fzero;

    for (int kt = 0; kt < 16; ++kt) {
        __syncthreads();
        // stage V tile transposed + swizzled
#pragma unroll
        for (int it = 0; it < 2; ++it) {
            int idx = threadIdx.x + it * 256;
            int mloc = idx >> 3, d8 = idx & 7;
            bf16x8 v = ld8(Vtb + (long)(kt * 64 + mloc) * CC + h * DKK + d8 * 8);
#pragma unroll
            for (int i = 0; i < 8; ++i) {
                int d = d8 * 8 + i;
                int sw = (((d >> 3) ^ d) & 7) * 8;
                vtile[d * 64 + (mloc ^ sw)] = v[i];
            }
        }
        __syncthreads();

        // S = Q K^T
        f32x4 s[4];
#pragma unroll
        for (int ct = 0; ct < 4; ++ct) s[ct] = fzero;
        const bf16* kp = Ktb + (long)(kt * 64 + l15) * CC + h * DKK + quad * 8;
#pragma unroll
        for (int ct = 0; ct < 4; ++ct) {
            bf16x8 bk0 = ld8(kp + ct * 16 * CC);
            bf16x8 bk1 = ld8(kp + ct * 16 * CC + 32);
            s[ct] = __builtin_amdgcn_mfma_f32_16x16x32_bf16(aq0, bk0, s[ct], 0, 0, 0);
            s[ct] = __builtin_amdgcn_mfma_f32_16x16x32_bf16(aq1, bk1, s[ct], 0, 0, 0);
        }

        // online softmax
        float pv[4][4], tmax[4], rsum[4], alpha[4];
#pragma unroll
        for (int ct = 0; ct < 4; ++ct)
#pragma unroll
            for (int r = 0; r < 4; ++r) pv[ct][r] = s[ct][r] * 0.125f + bh;
#pragma unroll
        for (int r = 0; r < 4; ++r)
            tmax[r] = fmaxf(fmaxf(pv[0][r], pv[1][r]), fmaxf(pv[2][r], pv[3][r]));
#pragma unroll
        for (int off = 1; off < 16; off <<= 1)
#pragma unroll
            for (int r = 0; r < 4; ++r)
                tmax[r] = fmaxf(tmax[r], __shfl_xor(tmax[r], off, 16));
#pragma unroll
        for (int r = 0; r < 4; ++r) {
            float mn = fmaxf(mrow[r], tmax[r]);
            alpha[r] = __expf(mrow[r] - mn);
            mrow[r] = mn;
            rsum[r] = 0.f;
        }
#pragma unroll
        for (int ct = 0; ct < 4; ++ct)
#pragma unroll
            for (int r = 0; r < 4; ++r) {
                pv[ct][r] = __expf(pv[ct][r] - mrow[r]);
                rsum[r] += pv[ct][r];
            }
#pragma unroll
        for (int off = 1; off < 16; off <<= 1)
#pragma unroll
            for (int r = 0; r < 4; ++r)
                rsum[r] += __shfl_xor(rsum[r], off, 16);
#pragma unroll
        for (int r = 0; r < 4; ++r) {
            lrow[r] = lrow[r] * alpha[r] + rsum[r];
#pragma unroll
            for (int ct = 0; ct < 4; ++ct) oacc[ct][r] *= alpha[r];
        }

        // P: D-layout -> LDS -> A-layout
        bf16* pl = &ptile[w][0];
#pragma unroll
        for (int ct = 0; ct < 4; ++ct)
#pragma unroll
            for (int r = 0; r < 4; ++r)
                pl[(quad * 4 + r) * 72 + ct * 16 + l15] = (bf16)pv[ct][r];
        __syncthreads();

        // O += P V
#pragma unroll
        for (int ks = 0; ks < 2; ++ks) {
            bf16x8 ap = ld8(&ptile[w][l15 * 72 + ks * 32 + quad * 8]);
#pragma unroll
            for (int ct = 0; ct < 4; ++ct) {
                int d = ct * 16 + l15;
                int sw = (((d >> 3) ^ d) & 7) * 8;
                bf16x8 bv = ld8(&vtile[d * 64 + ((ks * 32 + quad * 8) ^ sw)]);
                oacc[ct] = __builtin_amdgcn_mfma_f32_16x16x32_bf16(ap, bv, oacc[ct], 0, 0, 0);
            }
        }
    }

    float inv[4];
#pragma unroll
    for (int r = 0; r < 4; ++r) inv[r] = 1.f / lrow[r];
#pragma unroll
    for (int ct = 0; ct < 4; ++ct)
#pragma unroll
        for (int r = 0; r < 4; ++r)
            Otb[(long)(m0 + quad * 4 + r) * CC + h * DKK + ct * 16 + l15] =
                (bf16)(oacc[ct][r] * inv[r]);
}

// ---------------------------------------------------------------------------
// proj: p[b,o,n] = Wproj . ot[b,n,:]^T, fp32 out; blockIdx.z = batch
// ---------------------------------------------------------------------------
__global__ __launch_bounds__(256) void gemm_ntf(const bf16* __restrict__ A,
                                                const bf16* __restrict__ Bt,
                                                float* __restrict__ C) {
    const f32x4 fzero = {0.f, 0.f, 0.f, 0.f};
    int b = blockIdx.z;
    const bf16* Btb = Bt + (size_t)b * NN * CC;
    float* Cb = C + (size_t)b * CC * NN;
    int w = threadIdx.x >> 6, lane = threadIdx.x & 63;
    int quad = lane >> 4, l15 = lane & 15;
    long m0 = (long)blockIdx.x * 64 + w * 16;
    long n0 = (long)blockIdx.y * 64;
    f32x4 acc[4];
#pragma unroll
    for (int ct = 0; ct < 4; ++ct) acc[ct] = fzero;
    const bf16* Ap = A + (m0 + l15) * CC + quad * 8;
    const bf16* Bp = Btb + (n0 + l15) * CC + quad * 8;
#pragma unroll 2
    for (int k0 = 0; k0 < 512; k0 += 32) {
        bf16x8 a = ld8(Ap + k0);
#pragma unroll
        for (int ct = 0; ct < 4; ++ct) {
            bf16x8 bv = ld8(Bp + k0 + (long)ct * 16 * CC);
            acc[ct] = __builtin_amdgcn_mfma_f32_16x16x32_bf16(a, bv, acc[ct], 0, 0, 0);
        }
    }
#pragma unroll
    for (int ct = 0; ct < 4; ++ct)
#pragma unroll
        for (int r = 0; r < 4; ++r)
            Cb[(m0 + quad * 4 + r) * NN + n0 + ct * 16 + l15] = acc[ct][r];
}

// ---------------------------------------------------------------------------
// BN batch stats folded into scale/shift (fp32 p = d_out)
// ---------------------------------------------------------------------------
__global__ __launch_bounds__(256) void bnstats_kernel(const float* __restrict__ p,
                                                      const float* __restrict__ gamma,
                                                      const float* __restrict__ beta,
                                                      float* __restrict__ stats) {
    int c = blockIdx.x, t = threadIdx.x;
    float s = 0.f, ss = 0.f;
    for (int b = 0; b < BB; ++b) {
        const float* base = p + ((long)(b * CC + c)) * NN;
        for (int n = t; n < NN; n += 256) {
            float v = base[n];
            s += v; ss += v * v;
        }
    }
    __shared__ float rs[256], rss[256];
    rs[t] = s; rss[t] = ss;
    __syncthreads();
    for (int st = 128; st > 0; st >>= 1) {
        if (t < st) { rs[t] += rs[t + st]; rss[t] += rss[t + st]; }
        __syncthreads();
    }
    if (t == 0) {
        float mean = rs[0] * (1.f / 16384.f);
        float var = rss[0] * (1.f / 16384.f) - mean * mean;
        float rstd = rsqrtf(var + 1e-5f);
        float sc = gamma[c] * rstd;
        stats[c * 2] = sc;
        stats[c * 2 + 1] = beta[c] - mean * sc;
    }
}

// ---------------------------------------------------------------------------
// y = x + bn(p); LayerNorm over C per pixel; fp32 in-place on d_out
// ---------------------------------------------------------------------------
__global__ __launch_bounds__(256) void final_kernel(const float* __restrict__ x,
                                                    const float* __restrict__ p,
                                                    const float* __restrict__ stats,
                                                    const float* __restrict__ lg,
                                                    const float* __restrict__ lb,
                                                    float* __restrict__ out) {
    int blk = blockIdx.x;
    int b = blk >> 6;
    int pix0 = (blk & 63) * 64;
    int sub = threadIdx.x >> 6, px = threadIdx.x & 63;
    float s = 0.f, ss = 0.f;
    for (int i = 0; i < 128; ++i) {
        int c = i * 4 + sub;
        long idx = ((long)(b * CC + c)) * NN + pix0 + px;
        float y = x[idx] + p[idx] * stats[c * 2] + stats[c * 2 + 1];
        s += y; ss += y * y;
    }
    __shared__ float rs[4][64], rss[4][64];
    rs[sub][px] = s; rss[sub][px] = ss;
    __syncthreads();
    float sum = rs[0][px] + rs[1][px] + rs[2][px] + rs[3][px];
    float sq  = rss[0][px] + rss[1][px] + rss[2][px] + rss[3][px];
    float mu = sum * (1.f / 512.f);
    float var = sq * (1.f / 512.f) - mu * mu;
    float rstd = rsqrtf(var + 1e-5f);
    for (int i = 0; i < 128; ++i) {
        int c = i * 4 + sub;
        long idx = ((long)(b * CC + c)) * NN + pix0 + px;
        float y = x[idx] + p[idx] * stats[c * 2] + stats[c * 2 + 1];
        out[idx] = (y - mu) * rstd * lg[c] + lb[c];
    }
}

// ---------------------------------------------------------------------------
extern "C" void kernel_launch(void* const* d_in, const int* in_sizes, int n_in,
                              void* d_out, int out_size, void* d_ws, size_t ws_size,
                              hipStream_t stream) {
    (void)in_sizes; (void)n_in; (void)out_size;
    const float* x     = (const float*)d_in[0];
    const float* Wq    = (const float*)d_in[1];
    const float* Wk    = (const float*)d_in[2];
    const float* Wv    = (const float*)d_in[3];
    const float* bias  = (const float*)d_in[4];
    const float* Wproj = (const float*)d_in[5];
    const float* bng   = (const float*)d_in[6];
    const float* bnb   = (const float*)d_in[7];
    const float* lng   = (const float*)d_in[8];
    const float* lnb   = (const float*)d_in[9];
    float* out = (float*)d_out;   // fp32 output (verified R9)

    char* ws = (char*)d_ws;
    size_t off = 0;
    auto alloc = [&](size_t bytes) {
        char* pp = ws + off;
        off += (bytes + 255) & ~(size_t)255;
        return pp;
    };
    bf16* Wqb = (bf16*)alloc((size_t)CC * CC * 2);          // 0.52 MB
    bf16* Wpb = (bf16*)alloc((size_t)CC * CC * 2);          // 0.52 MB
    float* stats = (float*)alloc(512 * 2 * sizeof(float));

    // Layout A (fully batched) needs ~47 MB; layout B (per-batch) ~11.6 MB.
    size_t needA = off + ((size_t)CC * 2048 * 2 * 2)        // Wkf+Wvf 4.2 MB
                 + ((size_t)BB * NN * CC * 2)               // xt_all 16.8
                 + ((size_t)BB * NRR * CC * 2 * 2)          // kt+vt   8.4
                 + ((size_t)BB * NN * CC * 2) + 4096;       // ot_all 16.8

    if (ws_size >= needA) {
        // ---- layout A: one launch per stage, full batch in grid.z ----
        bf16* Wkf = (bf16*)alloc((size_t)CC * 2048 * 2);
        bf16* Wvf = (bf16*)alloc((size_t)CC * 2048 * 2);
        bf16* xt  = (bf16*)alloc((size_t)BB * NN * CC * 2);
        bf16* kt  = (bf16*)alloc((size_t)BB * NRR * CC * 2);
        bf16* vt  = (bf16*)alloc((size_t)BB * NRR * CC * 2);
        bf16* ot  = (bf16*)alloc((size_t)BB * NN * CC * 2);

        wcvt_kernel<<<1024, 256, 0, stream>>>(Wq, Wproj, Wqb, Wpb);
        wperm_kernel<<<4096, 256, 0, stream>>>(Wk, Wv, Wkf, Wvf);
        transpose_kernel<<<dim3(64, 8, BB), 256, 0, stream>>>(x, xt);
        gemm_kv<<<dim3(16, 8, BB * 2), 256, 0, stream>>>(xt, Wkf, Wvf, kt, vt);
        attn_kernel<<<dim3(64, NHH, BB), 256, 0, stream>>>(xt, Wqb, kt, vt, bias, ot);
        gemm_ntf<<<dim3(8, 64, BB), 256, 0, stream>>>(Wpb, ot, out);
    } else {
        // ---- layout B: per-batch loop, Wkf/Wvf overlay out slice 3 ----
        bf16* Wkf = (bf16*)(out + (size_t)3 * CC * NN);
        bf16* Wvf = Wkf + (size_t)CC * 2048;
        bf16* xt = (bf16*)alloc((size_t)NN * CC * 2);
        bf16* kt = (bf16*)alloc((size_t)NRR * CC * 2);
        bf16* vt = (bf16*)alloc((size_t)NRR * CC * 2);
        bf16* ot = (bf16*)alloc((size_t)NN * CC * 2);

        wcvt_kernel<<<1024, 256, 0, stream>>>(Wq, Wproj, Wqb, Wpb);
        wperm_kernel<<<4096, 256, 0, stream>>>(Wk, Wv, Wkf, Wvf);
        for (int b = 0; b < BB; ++b) {
            const float* xb = x + (size_t)b * CC * NN;
            float* pb = out + (size_t)b * CC * NN;
            transpose_kernel<<<dim3(64, 8, 1), 256, 0, stream>>>(xb, xt);
            gemm_kv<<<dim3(16, 8, 2), 256, 0, stream>>>(xt, Wkf, Wvf, kt, vt);
            attn_kernel<<<dim3(64, NHH, 1), 256, 0, stream>>>(xt, Wqb, kt, vt, bias, ot);
            gemm_ntf<<<dim3(8, 64, 1), 256, 0, stream>>>(Wpb, ot, pb);
        }
    }

    bnstats_kernel<<<512, 256, 0, stream>>>(out, bng, bnb, stats);
    final_kernel<<<256, 256, 0, stream>>>(x, out, stats, lng, lnb, out);
}